// Round 10
// baseline (183.614 us; speedup 1.0000x reference)
//
#include <hip/hip_runtime.h>

// SparseNodeConv: out = segment_sum((X@W)[edge_dst] by edge_src) + X@R + bias
// Strategy: AX = segment_sum(X[dst] by src)  (aggregate RAW features, linearity)
//           out = [AX | X](bf16) @ [W; R](bf16) + bias   via MFMA 16x16x32 bf16
//
// Sort config = round-8 (best measured): BSH=8 (196 buckets), CHUNK=4096.
// k_agg = plane-major hybrid: X stored as 4 planes of 32 cols (3.2MB each,
//   fits XCD L2); gridDim.y=plane with x-fastest dispatch -> one plane hot
//   at a time (round6 proved FETCH 147->64MB); instruction pattern = round8's
//   uint4 gather: 16 groups x 4 lanes x 16B = 16 edges per VMEM instr, so
//   total row-load instrs across 4 passes == round8's row-major count.
//   Cross-group reduce (xor 4,8,16,32) once per node per plane.
// N = 50000, E = 1600000, D = 128. Assumes N < 65536 (dst fits 16 bits).

typedef __attribute__((ext_vector_type(8))) short bf16x8;
typedef __attribute__((ext_vector_type(4))) float f32x4;

#define BSH 8       // coarse bucket = 256 nodes
#define CHUNK 4096  // edges per k_bucket block

__device__ __forceinline__ unsigned f2bf(float f) {
  unsigned u = __float_as_uint(f);
  return (u + 0x7fffu + ((u >> 16) & 1u)) >> 16;  // RNE
}
__device__ __forceinline__ unsigned pack2(float lo, float hi) {
  return f2bf(lo) | (f2bf(hi) << 16);
}
__device__ __forceinline__ float bflo(unsigned v) { return __uint_as_float(v << 16); }
__device__ __forceinline__ float bfhi(unsigned v) { return __uint_as_float(v & 0xffff0000u); }

// ---------- fused: X (f32) -> Xq (bf16, 4 quarter-planes) + coarse hist ----------
// Xq2[plane][node][8 uint2]  (plane = 32 cols = 64B per node row)
__global__ __launch_bounds__(256) void k_convhist(const float4* __restrict__ X,
                                                  uint2* __restrict__ Xq2, int n4,
                                                  const int* __restrict__ src,
                                                  int* __restrict__ ccnt,
                                                  int E_, int K_, int N_) {
  __shared__ int h[256];
  if (threadIdx.x < K_) h[threadIdx.x] = 0;
  __syncthreads();
  int stride = gridDim.x * blockDim.x;
  int gtid = blockIdx.x * blockDim.x + threadIdx.x;
  for (int i = gtid; i < n4; i += stride) {
    float4 v = X[i];
    uint2 o;
    o.x = pack2(v.x, v.y);
    o.y = pack2(v.z, v.w);
    int node = i >> 5;          // 32 float4 per 128-col row
    int plane = (i & 31) >> 3;  // 8 float4 per 32-col quarter
    int w = i & 7;              // uint2 index within quarter row
    Xq2[(size_t)plane * N_ * 8 + node * 8 + w] = o;
  }
  for (int i = gtid; i < E_; i += stride)
    atomicAdd(&h[((unsigned)src[i]) >> BSH], 1);
  __syncthreads();
  if (threadIdx.x < K_) {
    int c = h[threadIdx.x];
    if (c > 0) atomicAdd(&ccnt[threadIdx.x], c);
  }
}

// ---------- scan helper (256 threads, has __syncthreads) ----------
__device__ __forceinline__ int incl_scan256(int v, int tid) {
  int lane = tid & 63, w = tid >> 6;
  int x = v;
#pragma unroll
  for (int d = 1; d < 64; d <<= 1) {
    int o = __shfl_up(x, d, 64);
    if (lane >= d) x += o;
  }
  __shared__ int wsum[4];
  if (lane == 63) wsum[w] = x;
  __syncthreads();
  if (w > 0) x += wsum[0];
  if (w > 1) x += wsum[1];
  if (w > 2) x += wsum[2];
  return x;
}

// ---------- pass A: coarse scatter into 256-node buckets ----------
// pack = (src&255)<<16 | dst   (dst < 65536)
__global__ __launch_bounds__(256) void k_bucket(const int* __restrict__ src,
                                                const int* __restrict__ dst,
                                                const int* __restrict__ ccnt,
                                                int* __restrict__ cursor0,
                                                unsigned* __restrict__ packs,
                                                int E_, int K_) {
  __shared__ int lcnt[256];
  __shared__ int lbase[256];
  __shared__ unsigned lsrc[CHUNK];
  __shared__ unsigned ldst[CHUNK];
  int tid = threadIdx.x;
  // in-block exclusive scan of coarse counts -> absolute bucket bases
  int cv = (tid < K_) ? ccnt[tid] : 0;
  int cincl = incl_scan256(cv, tid);
  int cbaseL = cincl - cv;
  lcnt[tid] = 0;
  __syncthreads();
  int base = blockIdx.x * CHUNK;
  int n = min(CHUNK, E_ - base);
  for (int i = tid; i < n; i += 256) {
    unsigned s = (unsigned)src[base + i];
    unsigned d = (unsigned)dst[base + i];
    lsrc[i] = s;
    ldst[i] = d;
    atomicAdd(&lcnt[s >> BSH], 1);
  }
  __syncthreads();
  if (tid < K_) {
    int c = lcnt[tid];
    int r = (c > 0) ? atomicAdd(&cursor0[tid], c) : 0;
    lbase[tid] = cbaseL + r;
    lcnt[tid] = 0;  // reuse as local rank cursor
  }
  __syncthreads();
  for (int i = tid; i < n; i += 256) {
    unsigned s = lsrc[i], d = ldst[i];
    int b = s >> BSH;
    int r = atomicAdd(&lcnt[b], 1);
    packs[lbase[b] + r] = ((s & 255u) << 16) | d;
  }
}

// ---------- pass B: per-node hist + scan + fine scatter + offs write ----------
__global__ __launch_bounds__(256) void k_fine(const int* __restrict__ ccnt,
                                              const unsigned* __restrict__ packs,
                                              unsigned short* __restrict__ sdst,
                                              int* __restrict__ offs,
                                              int N_, int E_, int K_) {
  __shared__ int lcnt[256];
  __shared__ int lbase[256];
  int tid = threadIdx.x;
  int b = blockIdx.x;
  // in-block scan of coarse counts -> this bucket's [beg, beg+n)  (K <= 256)
  int cv = (tid < K_) ? ccnt[tid] : 0;
  int cincl = incl_scan256(cv, tid);
  __shared__ int sh_beg, sh_n;
  if (tid == b) {
    sh_beg = cincl - cv;
    sh_n = cv;
  }
  lcnt[tid] = 0;
  __syncthreads();
  int beg = sh_beg;
  int n = sh_n;
  int nodeBase = b << BSH;
  int nNodes = min(256, N_ - nodeBase);
  // per-node histogram (LDS atomics)
  for (int i = tid; i < n; i += 256) atomicAdd(&lcnt[packs[beg + i] >> 16], 1);
  __syncthreads();
  int v = lcnt[tid];
  int incl = incl_scan256(v, tid);
  int excl = incl - v;
  lbase[tid] = excl;
  if (tid < nNodes) offs[nodeBase + tid] = beg + excl;
  if (b == gridDim.x - 1 && tid == 0) offs[N_] = E_;
  __syncthreads();
  lcnt[tid] = 0;  // reuse as fine cursor
  __syncthreads();
  for (int i = tid; i < n; i += 256) {
    unsigned p = packs[beg + i];
    int sl = p >> 16;
    int r = atomicAdd(&lcnt[sl], 1);
    sdst[beg + lbase[sl] + r] = (unsigned short)(p & 0xffffu);
  }
}

// ---------- aggregation (per feature-quarter plane) ----------
// wave = 1 node; 16 groups x 4 lanes; group g handles edge j+g; 4 lanes x
// uint4 = one 64B plane-row -> 16 edges per VMEM instruction.
__global__ __launch_bounds__(256) void k_agg(const uint4* __restrict__ Xq4,
                                             const int* __restrict__ offs,
                                             const unsigned short* __restrict__ sdst,
                                             uint4* __restrict__ AXq4, int N_) {
  int node = (blockIdx.x * 256 + threadIdx.x) >> 6;
  if (node >= N_) return;
  int lane = threadIdx.x & 63;
  int g = lane >> 2, c = lane & 3;
  const uint4* Xp = Xq4 + (size_t)blockIdx.y * N_ * 4;
  int beg = offs[node], end = offs[node + 1];
  float a0 = 0.f, a1 = 0.f, a2 = 0.f, a3 = 0.f;
  float a4 = 0.f, a5 = 0.f, a6 = 0.f, a7 = 0.f;
  int j = beg;
#pragma unroll 2
  for (; j + 16 <= end; j += 16) {
    int e = sdst[j + g];
    uint4 v = Xp[(size_t)e * 4 + c];
    a0 += bflo(v.x); a1 += bfhi(v.x);
    a2 += bflo(v.y); a3 += bfhi(v.y);
    a4 += bflo(v.z); a5 += bfhi(v.z);
    a6 += bflo(v.w); a7 += bfhi(v.w);
  }
  if (j + g < end) {  // tail: per-4-lane-group predicate
    int e = sdst[j + g];
    uint4 v = Xp[(size_t)e * 4 + c];
    a0 += bflo(v.x); a1 += bfhi(v.x);
    a2 += bflo(v.y); a3 += bfhi(v.y);
    a4 += bflo(v.z); a5 += bfhi(v.z);
    a6 += bflo(v.w); a7 += bfhi(v.w);
  }
  // reduce across 16 groups (lane bits 2..5), once per node per plane
#pragma unroll
  for (int m = 4; m < 64; m <<= 1) {
    a0 += __shfl_xor(a0, m, 64); a1 += __shfl_xor(a1, m, 64);
    a2 += __shfl_xor(a2, m, 64); a3 += __shfl_xor(a3, m, 64);
    a4 += __shfl_xor(a4, m, 64); a5 += __shfl_xor(a5, m, 64);
    a6 += __shfl_xor(a6, m, 64); a7 += __shfl_xor(a7, m, 64);
  }
  if (g == 0) {
    uint4 o;
    o.x = pack2(a0, a1);
    o.y = pack2(a2, a3);
    o.z = pack2(a4, a5);
    o.w = pack2(a6, a7);
    AXq4[(size_t)blockIdx.y * N_ * 4 + node * 4 + c] = o;
  }
}

// ---------- GEMM: out[N,128] = AX@W + X@R + bias (MFMA 16x16x32 bf16) ----------
// A operands read from quarter-major planes: fragment kk == plane kk.
__global__ __launch_bounds__(256) void k_gemm(const unsigned* __restrict__ AXq,
                                              const unsigned* __restrict__ Xq,
                                              const float* __restrict__ Wg,
                                              const float* __restrict__ Rg,
                                              const float* __restrict__ bias,
                                              float* __restrict__ out, int N_) {
  __shared__ __align__(16) unsigned short Bt[128][136];
  int tid = threadIdx.x;
  int wave = tid >> 6, lane = tid & 63;
  int r = lane & 15, g = lane >> 4;
  int rowBase = (blockIdx.x * 4 + wave) * 16;
  int arow = rowBase + r;
  if (arow >= N_) arow = 0;  // clamp; stores are guarded

  bf16x8 fa[4], fx[4];
#pragma unroll
  for (int kk = 0; kk < 4; ++kk) {
    fa[kk] = *(const bf16x8*)(AXq + (size_t)kk * N_ * 16 + (size_t)arow * 16 + g * 4);
    fx[kk] = *(const bf16x8*)(Xq + (size_t)kk * N_ * 16 + (size_t)arow * 16 + g * 4);
  }

  f32x4 acc[8];
#pragma unroll
  for (int n = 0; n < 8; ++n) acc[n] = (f32x4){0.f, 0.f, 0.f, 0.f};

  for (int e = tid; e < 128 * 32; e += 256) {
    int c4 = (e & 31) * 4;
    int k = e >> 5;
    float4 v = *(const float4*)&Wg[k * 128 + c4];
    Bt[c4 + 0][k] = (unsigned short)f2bf(v.x);
    Bt[c4 + 1][k] = (unsigned short)f2bf(v.y);
    Bt[c4 + 2][k] = (unsigned short)f2bf(v.z);
    Bt[c4 + 3][k] = (unsigned short)f2bf(v.w);
  }
  __syncthreads();
#pragma unroll
  for (int n = 0; n < 8; ++n) {
    int col = n * 16 + r;
#pragma unroll
    for (int kk = 0; kk < 4; ++kk) {
      bf16x8 fb = *(const bf16x8*)&Bt[col][kk * 32 + g * 8];
      acc[n] = __builtin_amdgcn_mfma_f32_16x16x32_bf16(fa[kk], fb, acc[n], 0, 0, 0);
    }
  }
  __syncthreads();

  for (int e = tid; e < 128 * 32; e += 256) {
    int c4 = (e & 31) * 4;
    int k = e >> 5;
    float4 v = *(const float4*)&Rg[k * 128 + c4];
    Bt[c4 + 0][k] = (unsigned short)f2bf(v.x);
    Bt[c4 + 1][k] = (unsigned short)f2bf(v.y);
    Bt[c4 + 2][k] = (unsigned short)f2bf(v.z);
    Bt[c4 + 3][k] = (unsigned short)f2bf(v.w);
  }
  __syncthreads();
#pragma unroll
  for (int n = 0; n < 8; ++n) {
    int col = n * 16 + r;
#pragma unroll
    for (int kk = 0; kk < 4; ++kk) {
      bf16x8 fb = *(const bf16x8*)&Bt[col][kk * 32 + g * 8];
      acc[n] = __builtin_amdgcn_mfma_f32_16x16x32_bf16(fx[kk], fb, acc[n], 0, 0, 0);
    }
  }

#pragma unroll
  for (int n = 0; n < 8; ++n) {
    int col = n * 16 + r;
    float bv = bias[col];
#pragma unroll
    for (int jj = 0; jj < 4; ++jj) {
      int row = rowBase + g * 4 + jj;
      if (row < N_) out[(size_t)row * 128 + col] = acc[n][jj] + bv;
    }
  }
}

extern "C" void kernel_launch(void* const* d_in, const int* in_sizes, int n_in,
                              void* d_out, int out_size, void* d_ws, size_t ws_size,
                              hipStream_t stream) {
  const float* X = (const float*)d_in[0];
  const int* esrc = (const int*)d_in[1];
  const int* edst = (const int*)d_in[2];
  const float* Wg = (const float*)d_in[3];
  const float* Rg = (const float*)d_in[4];
  const float* bias = (const float*)d_in[5];
  float* out = (float*)d_out;

  int ND = in_sizes[0];  // N*D
  int E = in_sizes[1];
  int N = ND / 128;
  int K = (N + 255) >> BSH;  // 196 coarse buckets

  char* ws = (char*)d_ws;
  size_t off = 0;
  auto wsalloc = [&](size_t b) {
    char* p = ws + off;
    off = (off + b + 255) & ~(size_t)255;
    return p;
  };
  int* offs = (int*)wsalloc((size_t)(N + 1) * 4);
  unsigned short* sdst = (unsigned short*)wsalloc((size_t)E * 2);
  unsigned* Xq = (unsigned*)wsalloc((size_t)N * 64 * 4);   // 4 planes x N x 16 u32
  unsigned* AXq = (unsigned*)wsalloc((size_t)N * 64 * 4);
  // transient aliases inside the AXq region (dead before k_agg writes AXq):
  unsigned* packs = AXq;                       // E u32 (6.4MB <= 12.8MB)
  int* ccnt = (int*)(AXq + (size_t)E);         // 512 ints (K used)
  int* cursor0 = ccnt + 512;                   // 512 ints (K used)

  int nchunk = (E + CHUNK - 1) / CHUNK;
  hipMemsetAsync(ccnt, 0, 1024 * 4, stream);  // ccnt + cursor0
  k_convhist<<<512, 256, 0, stream>>>((const float4*)X, (uint2*)Xq, ND / 4,
                                      esrc, ccnt, E, K, N);
  k_bucket<<<nchunk, 256, 0, stream>>>(esrc, edst, ccnt, cursor0, packs, E, K);
  k_fine<<<K, 256, 0, stream>>>(ccnt, packs, sdst, offs, N, E, K);
  dim3 agrid((N + 3) / 4, 4);
  k_agg<<<agrid, 256, 0, stream>>>((const uint4*)Xq, offs, sdst,
                                   (uint4*)AXq, N);
  k_gemm<<<(N + 63) / 64, 256, 0, stream>>>(AXq, Xq, Wg, Rg, bias, out, N);
}

// Round 11
// 124.523 us; speedup vs baseline: 1.4745x; 1.4745x over previous
//
#include <hip/hip_runtime.h>

// SparseNodeConv: out = segment_sum((X@W)[edge_dst] by edge_src) + X@R + bias
// Strategy: AX = segment_sum(X[dst] by src)  (aggregate RAW features, linearity)
//           out = [AX | X](bf16) @ [W; R](bf16) + bias   via MFMA 16x16x32 bf16
//
// k_agg = round-9 optimum (row-major, uint4 quarter-gather, unroll 4):
//   45.9us @ 3.4TB/s L2-miss fill. Plane-split (r6/r10) proven worse: with
//   mean degree 32 the per-node fixed costs dominate 4 short passes.
// This round attacks the ~111us of sort/GEMM kernels:
//   k_bucket: SINGLE-PASS — per-thread 16 edges in registers, rank taken at
//     load via LDS atomic; no lsrc/ldst staging (LDS 34KB->2KB, 8 blocks/CU).
//   k_fine : 1024 threads/block (grid K=196 underfills 256 CUs; 4x per-block
//     parallelism).
//   k_gemm : stages PRE-TRANSPOSED bf16 B (Btg made once in k_convhist);
//     no per-block f32->bf16, half the staging bytes.
// N = 50000, E = 1600000, D = 128. Assumes N < 65536 (dst fits 16 bits).

typedef __attribute__((ext_vector_type(8))) short bf16x8;
typedef __attribute__((ext_vector_type(4))) float f32x4;

#define BSH 8       // coarse bucket = 256 nodes
#define CHUNK 4096  // edges per k_bucket block
#define EPT 16      // edges per thread in k_bucket (CHUNK/256)

__device__ __forceinline__ unsigned f2bf(float f) {
  unsigned u = __float_as_uint(f);
  return (u + 0x7fffu + ((u >> 16) & 1u)) >> 16;  // RNE
}
__device__ __forceinline__ unsigned pack2(float lo, float hi) {
  return f2bf(lo) | (f2bf(hi) << 16);
}
__device__ __forceinline__ float bflo(unsigned v) { return __uint_as_float(v << 16); }
__device__ __forceinline__ float bfhi(unsigned v) { return __uint_as_float(v & 0xffff0000u); }

// ---------- fused: X->Xb (row-major bf16), W/R -> Btg (bf16 transposed),
// ---------- coarse edge histogram ----------
__global__ __launch_bounds__(256) void k_convhist(const float4* __restrict__ X,
                                                  uint2* __restrict__ Xb, int n4,
                                                  const float* __restrict__ Wg,
                                                  const float* __restrict__ Rg,
                                                  unsigned short* __restrict__ Btg,
                                                  const int* __restrict__ src,
                                                  int* __restrict__ ccnt,
                                                  int E_, int K_) {
  __shared__ int h[256];
  if (threadIdx.x < K_) h[threadIdx.x] = 0;
  __syncthreads();
  int stride = gridDim.x * blockDim.x;
  int gtid = blockIdx.x * blockDim.x + threadIdx.x;
  for (int i = gtid; i < n4; i += stride) {
    float4 v = X[i];
    uint2 o;
    o.x = pack2(v.x, v.y);
    o.y = pack2(v.z, v.w);
    Xb[i] = o;
  }
  // Btg[m][col][k] = bf16(M[k][col]) ; m=0:W, m=1:R  (32768 elems)
  for (int i = gtid; i < 2 * 128 * 128; i += stride) {
    int m = i >> 14;
    int rem = i & 16383;
    int col = rem >> 7, k = rem & 127;
    const float* M = m ? Rg : Wg;
    Btg[i] = (unsigned short)f2bf(M[k * 128 + col]);
  }
  for (int i = gtid; i < E_; i += stride)
    atomicAdd(&h[((unsigned)src[i]) >> BSH], 1);
  __syncthreads();
  if (threadIdx.x < K_) {
    int c = h[threadIdx.x];
    if (c > 0) atomicAdd(&ccnt[threadIdx.x], c);
  }
}

// ---------- scan helper (256 threads, has __syncthreads) ----------
__device__ __forceinline__ int incl_scan256(int v, int tid) {
  int lane = tid & 63, w = tid >> 6;
  int x = v;
#pragma unroll
  for (int d = 1; d < 64; d <<= 1) {
    int o = __shfl_up(x, d, 64);
    if (lane >= d) x += o;
  }
  __shared__ int wsum[4];
  if (lane == 63) wsum[w] = x;
  __syncthreads();
  if (w > 0) x += wsum[0];
  if (w > 1) x += wsum[1];
  if (w > 2) x += wsum[2];
  return x;
}

// ---------- pass A: coarse scatter, SINGLE PASS (edges held in registers) ----------
// pack = (src&255)<<16 | dst   (dst < 65536)
__global__ __launch_bounds__(256) void k_bucket(const int* __restrict__ src,
                                                const int* __restrict__ dst,
                                                const int* __restrict__ ccnt,
                                                int* __restrict__ cursor0,
                                                unsigned* __restrict__ packs,
                                                int E_, int K_) {
  __shared__ int lcnt[256];
  __shared__ int lbase[256];
  int tid = threadIdx.x;
  // in-block exclusive scan of coarse counts -> absolute bucket bases
  int cv = (tid < K_) ? ccnt[tid] : 0;
  int cincl = incl_scan256(cv, tid);
  int cbaseL = cincl - cv;
  lcnt[tid] = 0;
  __syncthreads();
  int base = blockIdx.x * CHUNK;
  int n = min(CHUNK, E_ - base);
  unsigned epack[EPT];
  int erank[EPT];
  int ebkt[EPT];
#pragma unroll
  for (int u = 0; u < EPT; ++u) {
    int i = tid + u * 256;  // strided: coalesced loads
    if (i < n) {
      unsigned s = (unsigned)src[base + i];
      unsigned d = (unsigned)dst[base + i];
      int b = s >> BSH;
      ebkt[u] = b;
      erank[u] = atomicAdd(&lcnt[b], 1);
      epack[u] = ((s & 255u) << 16) | d;
    } else {
      ebkt[u] = -1;
    }
  }
  __syncthreads();
  if (tid < K_) {
    int c = lcnt[tid];
    int r = (c > 0) ? atomicAdd(&cursor0[tid], c) : 0;
    lbase[tid] = cbaseL + r;
  }
  __syncthreads();
#pragma unroll
  for (int u = 0; u < EPT; ++u)
    if (ebkt[u] >= 0) packs[lbase[ebkt[u]] + erank[u]] = epack[u];
}

// ---------- pass B: per-node hist + scan + fine scatter + offs (1024 thr) ----------
__global__ __launch_bounds__(1024) void k_fine(const int* __restrict__ ccnt,
                                               const unsigned* __restrict__ packs,
                                               unsigned short* __restrict__ sdst,
                                               int* __restrict__ offs,
                                               int N_, int E_, int K_) {
  __shared__ int lcnt[256];
  __shared__ int lbase[256];
  __shared__ int wsum[4];
  __shared__ int sh_beg, sh_n;
  int tid = threadIdx.x;
  int b = blockIdx.x;
  // --- coarse scan over ccnt (waves 0-3 only; all threads hit barriers) ---
  {
    int v = 0, x = 0;
    if (tid < 256) {
      v = (tid < K_) ? ccnt[tid] : 0;
      x = v;
#pragma unroll
      for (int d = 1; d < 64; d <<= 1) {
        int o = __shfl_up(x, d, 64);
        if ((tid & 63) >= d) x += o;
      }
      if ((tid & 63) == 63) wsum[tid >> 6] = x;
      lcnt[tid] = 0;
    }
    __syncthreads();
    if (tid == b) {  // b < K_ <= 256
      int w = tid >> 6;
      for (int ww = 0; ww < w; ++ww) x += wsum[ww];
      sh_beg = x - v;
      sh_n = v;
    }
    __syncthreads();
  }
  int beg = sh_beg, n = sh_n;
  int nodeBase = b << BSH;
  int nNodes = min(256, N_ - nodeBase);
  // --- per-node histogram (LDS atomics) ---
  for (int i = tid; i < n; i += 1024) atomicAdd(&lcnt[packs[beg + i] >> 16], 1);
  __syncthreads();
  // --- scan 256 node counts; write per-node CSR offs ---
  {
    int v = 0, x = 0;
    if (tid < 256) {
      v = lcnt[tid];
      x = v;
#pragma unroll
      for (int d = 1; d < 64; d <<= 1) {
        int o = __shfl_up(x, d, 64);
        if ((tid & 63) >= d) x += o;
      }
      if ((tid & 63) == 63) wsum[tid >> 6] = x;
    }
    __syncthreads();
    if (tid < 256) {
      int w = tid >> 6;
      for (int ww = 0; ww < w; ++ww) x += wsum[ww];
      int excl = x - v;
      lbase[tid] = excl;
      if (tid < nNodes) offs[nodeBase + tid] = beg + excl;
      lcnt[tid] = 0;  // reuse as fine cursor
    }
    if (b == 0 && tid == 0) offs[N_] = E_;
    __syncthreads();
  }
  // --- scatter to exact CSR slot (writes inside bucket's 16KB window) ---
  for (int i = tid; i < n; i += 1024) {
    unsigned p = packs[beg + i];
    int sl = p >> 16;
    int r = atomicAdd(&lcnt[sl], 1);
    sdst[beg + lbase[sl] + r] = (unsigned short)(p & 0xffffu);
  }
}

// ---------- aggregation: AXb[i] = sum over CSR segment i of Xb[dst] ----------
// one wave = one node; quarter q = edge j+q; 16 lanes x uint4 = one 256B row.
__global__ __launch_bounds__(256) void k_agg(const uint4* __restrict__ Xb4,
                                             const int* __restrict__ offs,
                                             const unsigned short* __restrict__ sdst,
                                             uint4* __restrict__ AXb4, int N_) {
  int node = (blockIdx.x * 256 + threadIdx.x) >> 6;
  if (node >= N_) return;
  int lane = threadIdx.x & 63;
  int q = lane >> 4, c = lane & 15;
  int beg = offs[node], end = offs[node + 1];
  float a0 = 0.f, a1 = 0.f, a2 = 0.f, a3 = 0.f;
  float a4 = 0.f, a5 = 0.f, a6 = 0.f, a7 = 0.f;
  int j = beg;
#pragma unroll 4
  for (; j + 4 <= end; j += 4) {
    int e = sdst[j + q];
    uint4 v = Xb4[(size_t)e * 16 + c];
    a0 += bflo(v.x); a1 += bfhi(v.x);
    a2 += bflo(v.y); a3 += bfhi(v.y);
    a4 += bflo(v.z); a5 += bfhi(v.z);
    a6 += bflo(v.w); a7 += bfhi(v.w);
  }
  if (j + q < end) {  // tail (16-lane-group-uniform predicate)
    int e = sdst[j + q];
    uint4 v = Xb4[(size_t)e * 16 + c];
    a0 += bflo(v.x); a1 += bfhi(v.x);
    a2 += bflo(v.y); a3 += bfhi(v.y);
    a4 += bflo(v.z); a5 += bfhi(v.z);
    a6 += bflo(v.w); a7 += bfhi(v.w);
  }
  // cross-quarter reduce (once per node)
  a0 += __shfl_xor(a0, 16, 64); a1 += __shfl_xor(a1, 16, 64);
  a2 += __shfl_xor(a2, 16, 64); a3 += __shfl_xor(a3, 16, 64);
  a4 += __shfl_xor(a4, 16, 64); a5 += __shfl_xor(a5, 16, 64);
  a6 += __shfl_xor(a6, 16, 64); a7 += __shfl_xor(a7, 16, 64);
  a0 += __shfl_xor(a0, 32, 64); a1 += __shfl_xor(a1, 32, 64);
  a2 += __shfl_xor(a2, 32, 64); a3 += __shfl_xor(a3, 32, 64);
  a4 += __shfl_xor(a4, 32, 64); a5 += __shfl_xor(a5, 32, 64);
  a6 += __shfl_xor(a6, 32, 64); a7 += __shfl_xor(a7, 32, 64);
  if (q == 0) {
    uint4 o;
    o.x = pack2(a0, a1);
    o.y = pack2(a2, a3);
    o.z = pack2(a4, a5);
    o.w = pack2(a6, a7);
    AXb4[(size_t)node * 16 + c] = o;
  }
}

// ---------- GEMM: out[N,128] = AXb@W + Xb@R + bias (MFMA 16x16x32 bf16) ----------
// B staged from pre-transposed bf16 Btg[m][col][k] into padded LDS.
__global__ __launch_bounds__(256) void k_gemm(const unsigned* __restrict__ AXb,
                                              const unsigned* __restrict__ Xb,
                                              const unsigned short* __restrict__ Btg,
                                              const float* __restrict__ bias,
                                              float* __restrict__ out, int N_) {
  __shared__ __align__(16) unsigned short Bt[128][136];
  int tid = threadIdx.x;
  int wave = tid >> 6, lane = tid & 63;
  int r = lane & 15, g = lane >> 4;
  int rowBase = (blockIdx.x * 4 + wave) * 16;
  int arow = rowBase + r;
  if (arow >= N_) arow = 0;  // clamp; stores are guarded

  bf16x8 fa[4], fx[4];
  const bf16x8* pA = (const bf16x8*)(AXb + (size_t)arow * 64);
  const bf16x8* pX = (const bf16x8*)(Xb + (size_t)arow * 64);
#pragma unroll
  for (int kk = 0; kk < 4; ++kk) {
    fa[kk] = pA[kk * 4 + g];
    fx[kk] = pX[kk * 4 + g];
  }

  f32x4 acc[8];
#pragma unroll
  for (int n = 0; n < 8; ++n) acc[n] = (f32x4){0.f, 0.f, 0.f, 0.f};

  // pass 1: W^T
  for (int cth = tid; cth < 2048; cth += 256) {  // 2048 chunks of 8 shorts
    int col = cth >> 4, k0 = (cth & 15) * 8;
    *(uint4*)&Bt[col][k0] = *(const uint4*)&Btg[(col << 7) + k0];
  }
  __syncthreads();
#pragma unroll
  for (int n = 0; n < 8; ++n) {
    int col = n * 16 + r;
#pragma unroll
    for (int kk = 0; kk < 4; ++kk) {
      bf16x8 fb = *(const bf16x8*)&Bt[col][kk * 32 + g * 8];
      acc[n] = __builtin_amdgcn_mfma_f32_16x16x32_bf16(fa[kk], fb, acc[n], 0, 0, 0);
    }
  }
  __syncthreads();
  // pass 2: R^T
  for (int cth = tid; cth < 2048; cth += 256) {
    int col = cth >> 4, k0 = (cth & 15) * 8;
    *(uint4*)&Bt[col][k0] = *(const uint4*)&Btg[16384 + (col << 7) + k0];
  }
  __syncthreads();
#pragma unroll
  for (int n = 0; n < 8; ++n) {
    int col = n * 16 + r;
#pragma unroll
    for (int kk = 0; kk < 4; ++kk) {
      bf16x8 fb = *(const bf16x8*)&Bt[col][kk * 32 + g * 8];
      acc[n] = __builtin_amdgcn_mfma_f32_16x16x32_bf16(fx[kk], fb, acc[n], 0, 0, 0);
    }
  }

#pragma unroll
  for (int n = 0; n < 8; ++n) {
    int col = n * 16 + r;
    float bv = bias[col];
#pragma unroll
    for (int jj = 0; jj < 4; ++jj) {
      int row = rowBase + g * 4 + jj;
      if (row < N_) out[(size_t)row * 128 + col] = acc[n][jj] + bv;
    }
  }
}

extern "C" void kernel_launch(void* const* d_in, const int* in_sizes, int n_in,
                              void* d_out, int out_size, void* d_ws, size_t ws_size,
                              hipStream_t stream) {
  const float* X = (const float*)d_in[0];
  const int* esrc = (const int*)d_in[1];
  const int* edst = (const int*)d_in[2];
  const float* Wg = (const float*)d_in[3];
  const float* Rg = (const float*)d_in[4];
  const float* bias = (const float*)d_in[5];
  float* out = (float*)d_out;

  int ND = in_sizes[0];  // N*D
  int E = in_sizes[1];
  int N = ND / 128;
  int K = (N + 255) >> BSH;  // 196 coarse buckets

  char* ws = (char*)d_ws;
  size_t off = 0;
  auto wsalloc = [&](size_t b) {
    char* p = ws + off;
    off = (off + b + 255) & ~(size_t)255;
    return p;
  };
  int* offs = (int*)wsalloc((size_t)(N + 1) * 4);
  unsigned short* sdst = (unsigned short*)wsalloc((size_t)E * 2);
  unsigned short* Btg = (unsigned short*)wsalloc(2 * 128 * 128 * 2);
  unsigned* Xb = (unsigned*)wsalloc((size_t)N * 64 * 4);
  unsigned* AXb = (unsigned*)wsalloc((size_t)N * 64 * 4);
  // transient aliases inside the AXb region (dead before k_agg writes AXb):
  unsigned* packs = AXb;                       // E u32 (6.4MB <= 12.8MB)
  int* ccnt = (int*)(AXb + (size_t)E);         // 512 ints (K used)
  int* cursor0 = ccnt + 512;                   // 512 ints (K used)

  int nchunk = (E + CHUNK - 1) / CHUNK;
  hipMemsetAsync(ccnt, 0, 1024 * 4, stream);  // ccnt + cursor0
  k_convhist<<<512, 256, 0, stream>>>((const float4*)X, (uint2*)Xb, ND / 4,
                                      Wg, Rg, Btg, esrc, ccnt, E, K);
  k_bucket<<<nchunk, 256, 0, stream>>>(esrc, edst, ccnt, cursor0, packs, E, K);
  k_fine<<<K, 1024, 0, stream>>>(ccnt, packs, sdst, offs, N, E, K);
  k_agg<<<(N + 3) / 4, 256, 0, stream>>>((const uint4*)Xb, offs, sdst,
                                         (uint4*)AXb, N);
  k_gemm<<<(N + 63) / 64, 256, 0, stream>>>(AXb, Xb, Btg, bias, out, N);
}